// Round 9
// baseline (305.775 us; speedup 1.0000x reference)
//
#include <hip/hip_runtime.h>

// 2-layer tanh RNN, B=2048, S=512, I=1, H=64, O=1.
// One wave per batch element. Lane i owns hidden unit i. Weight rows live in
// VGPRs as PACKED F16 PAIRS (96 VGPRs). Core accumulation: v_pk_fma_f16 via
// INLINE ASM — round 8 evidence says the half2 a*b+c expressions did NOT
// fuse (VALU busy ~592cyc/wave/step matches mul+add, not fma); issue-cycle
// accounting across rounds 5-8 shows this kernel is VALU-issue-bound, so
// halving the packed-MAC stream (384->192cyc) is the lever.
// 4 independent half2 chains per matvec (depth 8); chains reduce to f32 via
// v_dot2_f32_f16 with (1,1) — f32 accumulate protects the 2.85e-3 threshold.
// h passes between steps through PING-PONG LDS buffers (read (k-1)&1, write
// k&1). h1[k] stored mid-iteration; phase B hides its store->load latency.
// Single-wave block -> in-order DS, no barriers.

#define HID 64
#define SEQ 512

typedef _Float16 half2_t __attribute__((ext_vector_type(2)));
typedef _Float16 half8_t __attribute__((ext_vector_type(8)));

struct H2x4 { half2_t h[4]; };   // one 16-B LDS chunk as 4 half2

__device__ __forceinline__ float tanh_fast(float x) {
    // tanh(x) = 1 - 2/(exp(2x)+1);  exp(2x) = exp2(x * 2*log2(e))
    float e = __builtin_amdgcn_exp2f(x * 2.8853900817779268f);  // v_exp_f32
    return 1.0f - 2.0f * __builtin_amdgcn_rcpf(e + 1.0f);       // v_rcp_f32
}

__device__ __forceinline__ float dot2(half2_t a, half2_t b, float c) {
    return __builtin_amdgcn_fdot2(a, b, c, false);   // v_dot2_f32_f16
}

// Guaranteed-fused packed f16 FMA: d = a*b + c (one v_pk_fma_f16).
__device__ __forceinline__ half2_t pkfma(half2_t a, half2_t b, half2_t c) {
    half2_t d;
    asm("v_pk_fma_f16 %0, %1, %2, %3" : "=v"(d) : "v"(a), "v"(b), "v"(c));
    return d;
}

__attribute__((amdgpu_waves_per_eu(2, 2)))
__global__ void __launch_bounds__(64)
rnn2_kernel(const float* __restrict__ x,      // [B][SEQ] (I=1)
            const float* __restrict__ W_ih0,  // [HID][1]
            const float* __restrict__ W_hh0,  // [HID][HID]
            const float* __restrict__ b_ih0,  // [HID]
            const float* __restrict__ b_hh0,  // [HID]
            const float* __restrict__ W_ih1,  // [HID][HID]
            const float* __restrict__ W_hh1,  // [HID][HID]
            const float* __restrict__ b_ih1,  // [HID]
            const float* __restrict__ b_hh1,  // [HID]
            const float* __restrict__ fc_W,   // [1][HID]
            const float* __restrict__ fc_b,   // [1]
            float* __restrict__ out)          // [B]
{
    __shared__ __align__(16) float    x_lds[SEQ];
    __shared__ __align__(16) _Float16 hbuf[2][2][HID];   // [pp][h1|h2][unit]

    const int lane = threadIdx.x;   // 0..63 = hidden unit
    const int b    = blockIdx.x;    // batch element

    // --- Weight rows -> packed f16 pairs in registers (96 VGPRs) ---
    half2_t w0h[HID / 2], wi1h[HID / 2], w1h[HID / 2];
#pragma unroll
    for (int j = 0; j < HID; j += 4) {
        const float4 a = *reinterpret_cast<const float4*>(&W_hh0[lane * HID + j]);
        const float4 c = *reinterpret_cast<const float4*>(&W_ih1[lane * HID + j]);
        const float4 d = *reinterpret_cast<const float4*>(&W_hh1[lane * HID + j]);
        w0h [j/2]   = half2_t{(_Float16)a.x, (_Float16)a.y};
        w0h [j/2+1] = half2_t{(_Float16)a.z, (_Float16)a.w};
        wi1h[j/2]   = half2_t{(_Float16)c.x, (_Float16)c.y};
        wi1h[j/2+1] = half2_t{(_Float16)c.z, (_Float16)c.w};
        w1h [j/2]   = half2_t{(_Float16)d.x, (_Float16)d.y};
        w1h [j/2+1] = half2_t{(_Float16)d.z, (_Float16)d.w};
    }
    const float win0  = W_ih0[lane];
    const float bias0 = b_ih0[lane] + b_hh0[lane];
    const float bias1 = b_ih1[lane] + b_hh1[lane];
    const half2_t one = half2_t{(_Float16)1.0f, (_Float16)1.0f};
    const half2_t zr  = half2_t{(_Float16)0.0f, (_Float16)0.0f};

    // --- Stage x sequence into LDS (coalesced, f32) ---
#pragma unroll
    for (int t = 0; t < SEQ / HID; ++t)
        x_lds[t * HID + lane] = x[(size_t)b * SEQ + t * HID + lane];

    // --- Prologue: hbuf[0] <- { h1[0], h2[-1]=0 } ---
    hbuf[0][1][lane] = (_Float16)0.0f;
    hbuf[0][0][lane] = (_Float16)tanh_fast(fmaf(x_lds[0], win0, bias0));

    // --- Main loop: iter k computes h1[k] and h2[k-1] ---
#pragma unroll 1
    for (int k = 1; k < SEQ; ++k) {
        const _Float16* rd1 = hbuf[(k - 1) & 1][0];   // h1[k-1]
        const _Float16* rd2 = hbuf[(k - 1) & 1][1];   // h2[k-2]
        _Float16*       wr1 = hbuf[k & 1][0];
        _Float16*       wr2 = hbuf[k & 1][1];

        // ---- phase A: pk-accumulate W_hh0.h1[k-1] and W_ih1.h1[k-1] ----
        half2_t p10 = zr, p11 = zr, p12 = zr, p13 = zr;   // a1 chains
        half2_t p20 = zr, p21 = zr, p22 = zr, p23 = zr;   // a2 chains
#pragma unroll
        for (int j = 0; j < 8; ++j) {
            const H2x4 c1 = __builtin_bit_cast(H2x4,
                *reinterpret_cast<const half8_t*>(&rd1[8 * j]));
            p10 = pkfma(w0h [4*j+0], c1.h[0], p10);
            p11 = pkfma(w0h [4*j+1], c1.h[1], p11);
            p12 = pkfma(w0h [4*j+2], c1.h[2], p12);
            p13 = pkfma(w0h [4*j+3], c1.h[3], p13);
            p20 = pkfma(wi1h[4*j+0], c1.h[0], p20);
            p21 = pkfma(wi1h[4*j+1], c1.h[1], p21);
            p22 = pkfma(wi1h[4*j+2], c1.h[2], p22);
            p23 = pkfma(wi1h[4*j+3], c1.h[3], p23);
        }
        // reduce a1 chains to f32, finish h1[k], store EARLY
        float a1a = dot2(p10, one, 0.0f);
        float a1b = dot2(p11, one, 0.0f);
        a1a = dot2(p12, one, a1a);
        a1b = dot2(p13, one, a1b);
        const float h1n = tanh_fast(a1a + a1b + fmaf(x_lds[k], win0, bias0));
        wr1[lane] = (_Float16)h1n;   // h1[k]; phase B below hides the latency

        // ---- phase B: pk-accumulate W_hh1.h2[k-2] ----
        half2_t p30 = zr, p31 = zr, p32 = zr, p33 = zr;
#pragma unroll
        for (int j = 0; j < 8; ++j) {
            const H2x4 c2 = __builtin_bit_cast(H2x4,
                *reinterpret_cast<const half8_t*>(&rd2[8 * j]));
            p30 = pkfma(w1h[4*j+0], c2.h[0], p30);
            p31 = pkfma(w1h[4*j+1], c2.h[1], p31);
            p32 = pkfma(w1h[4*j+2], c2.h[2], p32);
            p33 = pkfma(w1h[4*j+3], c2.h[3], p33);
        }
        float a2a = dot2(p20, one, 0.0f);
        float a2b = dot2(p21, one, 0.0f);
        a2a = dot2(p22, one, a2a);
        a2b = dot2(p23, one, a2b);
        a2a = dot2(p30, one, a2a);
        a2b = dot2(p31, one, a2b);
        a2a = dot2(p32, one, a2a);
        a2b = dot2(p33, one, a2b);
        const float h2n = tanh_fast(a2a + a2b + bias1);
        wr2[lane] = (_Float16)h2n;   // h2[k-1]
    }

    // --- Epilogue: h2[SEQ-1] from h1[SEQ-1] and h2[SEQ-2] (hbuf[1]) ---
    {
        const _Float16* rd1 = hbuf[(SEQ - 1) & 1][0];
        const _Float16* rd2 = hbuf[(SEQ - 1) & 1][1];
        float a2a = 0.f, a2b = 0.f;
#pragma unroll
        for (int j = 0; j < 8; ++j) {
            const H2x4 c1 = __builtin_bit_cast(H2x4,
                *reinterpret_cast<const half8_t*>(&rd1[8 * j]));
            const H2x4 c2 = __builtin_bit_cast(H2x4,
                *reinterpret_cast<const half8_t*>(&rd2[8 * j]));
            a2a = dot2(wi1h[4*j+0], c1.h[0], a2a);
            a2b = dot2(wi1h[4*j+1], c1.h[1], a2b);
            a2a = dot2(wi1h[4*j+2], c1.h[2], a2a);
            a2b = dot2(wi1h[4*j+3], c1.h[3], a2b);
            a2a = dot2(w1h [4*j+0], c2.h[0], a2a);
            a2b = dot2(w1h [4*j+1], c2.h[1], a2b);
            a2a = dot2(w1h [4*j+2], c2.h[2], a2a);
            a2b = dot2(w1h [4*j+3], c2.h[3], a2b);
        }
        const float h2last = tanh_fast(a2a + a2b + bias1);

        // --- Final FC: out[b] = sum_i h2last[i] * fc_W[i] + fc_b ---
        float v = h2last * fc_W[lane];
#pragma unroll
        for (int off = 32; off > 0; off >>= 1)
            v += __shfl_xor(v, off, 64);
        if (lane == 0)
            out[b] = v + fc_b[0];
    }
}

extern "C" void kernel_launch(void* const* d_in, const int* in_sizes, int n_in,
                              void* d_out, int out_size, void* d_ws, size_t ws_size,
                              hipStream_t stream) {
    const float* x     = (const float*)d_in[0];
    const float* W_ih0 = (const float*)d_in[1];
    const float* W_hh0 = (const float*)d_in[2];
    const float* b_ih0 = (const float*)d_in[3];
    const float* b_hh0 = (const float*)d_in[4];
    const float* W_ih1 = (const float*)d_in[5];
    const float* W_hh1 = (const float*)d_in[6];
    const float* b_ih1 = (const float*)d_in[7];
    const float* b_hh1 = (const float*)d_in[8];
    const float* fc_W  = (const float*)d_in[9];
    const float* fc_b  = (const float*)d_in[10];

    rnn2_kernel<<<dim3(2048), dim3(64), 0, stream>>>(
        x, W_ih0, W_hh0, b_ih0, b_hh0, W_ih1, W_hh1, b_ih1, b_hh1,
        fc_W, fc_b, (float*)d_out);
}

// Round 10
// 152.552 us; speedup vs baseline: 2.0044x; 2.0044x over previous
//
#include <hip/hip_runtime.h>

// 2-layer tanh RNN via MFMA. B=2048, S=512, I=1, H=64, O=1.
// 128 blocks x 256 threads; each block owns 16 sequences (batch cols).
// Wave w (of 4) owns M-tile rows [w*16, w*16+16) of all three matvecs.
// Per step per wave: 6 x mfma_f32_16x16x32_f16 (W_hh0.h1 | W_ih1.h1 +
// W_hh1.h2 chained) + 8 tanh. Weights live as A-fragments in VGPRs
// (loop-invariant, 24 regs/wave). h passes between steps through a
// ping-pong LDS buffer in [batch][unit] f16 layout (stride 72 units ->
// bank-balanced b64 writes and b128 fragment reads). One barrier/step.
// Fragment layouts: C/D col=lane&15,row=(lane>>4)*4+reg (verified m89);
// A/B: lane l&15 = row/col, k = kc*32 + (l>>4)*8 + i contiguous
// (matches refchecked m92/97 GEMM b128 frag loads).

#define SEQ 512
#define XS  17   // x_lds row stride in f32 words (odd -> bank spread)
#define HS  72   // h row stride in f16 units (144 B = 16 B multiple)

typedef _Float16 half4_t __attribute__((ext_vector_type(4)));
typedef _Float16 half8_t __attribute__((ext_vector_type(8)));
typedef float    floatx4 __attribute__((ext_vector_type(4)));

__device__ __forceinline__ float tanh_fast(float x) {
    // tanh(x) = 1 - 2/(exp(2x)+1)
    float e = __builtin_amdgcn_exp2f(x * 2.8853900817779268f);  // v_exp_f32
    return 1.0f - 2.0f * __builtin_amdgcn_rcpf(e + 1.0f);       // v_rcp_f32
}

__device__ __forceinline__ floatx4 mfma16(half8_t a, half8_t b, floatx4 c) {
    return __builtin_amdgcn_mfma_f32_16x16x32_f16(a, b, c, 0, 0, 0);
}

__global__ void __launch_bounds__(256)
rnn2_mfma_kernel(const float* __restrict__ x,      // [B][SEQ]
                 const float* __restrict__ W_ih0,  // [64][1]
                 const float* __restrict__ W_hh0,  // [64][64]
                 const float* __restrict__ b_ih0,  // [64]
                 const float* __restrict__ b_hh0,  // [64]
                 const float* __restrict__ W_ih1,  // [64][64]
                 const float* __restrict__ W_hh1,  // [64][64]
                 const float* __restrict__ b_ih1,  // [64]
                 const float* __restrict__ b_hh1,  // [64]
                 const float* __restrict__ fc_W,   // [1][64]
                 const float* __restrict__ fc_b,   // [1]
                 float* __restrict__ out)          // [B]
{
    __shared__ __align__(16) float    x_s[(SEQ + 1) * XS];  // +1 row: k=511 prefetch pad
    __shared__ __align__(16) _Float16 hb[2][2][16 * HS];    // [pingpong][h1|h2][n*HS+u]
    __shared__ float fcp[4][16];

    const int tid  = threadIdx.x;
    const int w    = tid >> 6;      // wave id == M-tile
    const int lane = tid & 63;
    const int g    = lane >> 4;     // 4-lane-group row of the fragment
    const int col  = lane & 15;     // batch column n
    const int bw   = blockIdx.x;    // group of 16 sequences

    // ---- stage x transposed: x_s[s*XS + n] = x[bw*16+n][s] (coalesced) ----
#pragma unroll
    for (int i = 0; i < (16 * SEQ) / 256; ++i) {
        const int e = i * 256 + tid;
        const int n = e >> 9, s = e & 511;
        x_s[s * XS + n] = x[((size_t)bw * 16 + n) * SEQ + s];
    }

    // ---- A-fragments for this wave's M-tile (rows m = w*16 + col) ----
    half8_t A0[2], Ai[2], Ah[2];    // W_hh0, W_ih1, W_hh1
    {
        const int m = w * 16 + col;
#pragma unroll
        for (int kc = 0; kc < 2; ++kc) {
            const int k0 = kc * 32 + g * 8;
            const float4 a = *(const float4*)&W_hh0[m * 64 + k0];
            const float4 b = *(const float4*)&W_hh0[m * 64 + k0 + 4];
            const float4 c = *(const float4*)&W_ih1[m * 64 + k0];
            const float4 d = *(const float4*)&W_ih1[m * 64 + k0 + 4];
            const float4 e2 = *(const float4*)&W_hh1[m * 64 + k0];
            const float4 f2 = *(const float4*)&W_hh1[m * 64 + k0 + 4];
            A0[kc] = half8_t{(_Float16)a.x, (_Float16)a.y, (_Float16)a.z, (_Float16)a.w,
                             (_Float16)b.x, (_Float16)b.y, (_Float16)b.z, (_Float16)b.w};
            Ai[kc] = half8_t{(_Float16)c.x, (_Float16)c.y, (_Float16)c.z, (_Float16)c.w,
                             (_Float16)d.x, (_Float16)d.y, (_Float16)d.z, (_Float16)d.w};
            Ah[kc] = half8_t{(_Float16)e2.x, (_Float16)e2.y, (_Float16)e2.z, (_Float16)e2.w,
                             (_Float16)f2.x, (_Float16)f2.y, (_Float16)f2.z, (_Float16)f2.w};
        }
    }

    // ---- per-lane row constants for rows u = w*16 + g*4 + r ----
    float win0f[4], b0f[4], b1f[4];
#pragma unroll
    for (int r = 0; r < 4; ++r) {
        const int u = w * 16 + g * 4 + r;
        win0f[r] = W_ih0[u];
        b0f[r]   = b_ih0[u] + b_hh0[u];
        b1f[r]   = b_ih1[u] + b_hh1[u];
    }

    __syncthreads();   // x_s ready

    // ---- prologue: h1[0] = tanh(win0*x0 + b0), h2[-1] = 0 -> buf 0 ----
    {
        const float xv0 = x_s[col];
        half4_t h1v, z = half4_t{(_Float16)0.f, (_Float16)0.f, (_Float16)0.f, (_Float16)0.f};
#pragma unroll
        for (int r = 0; r < 4; ++r)
            h1v[r] = (_Float16)tanh_fast(fmaf(win0f[r], xv0, b0f[r]));
        *(half4_t*)&hb[0][0][col * HS + w * 16 + g * 4] = h1v;
        *(half4_t*)&hb[0][1][col * HS + w * 16 + g * 4] = z;
    }
    __syncthreads();

    half8_t c1[2], c2[2];
    c1[0] = *(const half8_t*)&hb[0][0][col * HS + g * 8];
    c1[1] = *(const half8_t*)&hb[0][0][col * HS + 32 + g * 8];
    c2[0] = *(const half8_t*)&hb[0][1][col * HS + g * 8];
    c2[1] = *(const half8_t*)&hb[0][1][col * HS + 32 + g * 8];
    float xv = x_s[XS + col];

    // ---- main loop: iter k computes h1[k] and h2[k-1] ----
#pragma unroll 1
    for (int k = 1; k < SEQ; ++k) {
        const floatx4 z4 = floatx4{0.f, 0.f, 0.f, 0.f};
        floatx4 C1 = mfma16(A0[1], c1[1], mfma16(A0[0], c1[0], z4));
        floatx4 C2 = mfma16(Ah[1], c2[1], mfma16(Ah[0], c2[0],
                     mfma16(Ai[1], c1[1], mfma16(Ai[0], c1[0], z4))));

        const int pw = k & 1;
        half4_t h1v, h2v;
#pragma unroll
        for (int r = 0; r < 4; ++r)
            h1v[r] = (_Float16)tanh_fast(fmaf(win0f[r], xv, C1[r] + b0f[r]));
#pragma unroll
        for (int r = 0; r < 4; ++r)
            h2v[r] = (_Float16)tanh_fast(C2[r] + b1f[r]);

        *(half4_t*)&hb[pw][0][col * HS + w * 16 + g * 4] = h1v;  // h1[k]
        *(half4_t*)&hb[pw][1][col * HS + w * 16 + g * 4] = h2v;  // h2[k-1]
        __syncthreads();

        c1[0] = *(const half8_t*)&hb[pw][0][col * HS + g * 8];
        c1[1] = *(const half8_t*)&hb[pw][0][col * HS + 32 + g * 8];
        c2[0] = *(const half8_t*)&hb[pw][1][col * HS + g * 8];
        c2[1] = *(const half8_t*)&hb[pw][1][col * HS + 32 + g * 8];
        xv = x_s[(k + 1) * XS + col];   // pad row covers k=511
    }

    // ---- epilogue: h2[511] + fused FC ----
    {
        const floatx4 z4 = floatx4{0.f, 0.f, 0.f, 0.f};
        floatx4 C2 = mfma16(Ah[1], c2[1], mfma16(Ah[0], c2[0],
                     mfma16(Ai[1], c1[1], mfma16(Ai[0], c1[0], z4))));
        float v = 0.f;
#pragma unroll
        for (int r = 0; r < 4; ++r) {
            const int u = w * 16 + g * 4 + r;
            v += fc_W[u] * tanh_fast(C2[r] + b1f[r]);
        }
        v += __shfl_xor(v, 16, 64);
        v += __shfl_xor(v, 32, 64);
        if (lane < 16) fcp[w][lane] = v;
        __syncthreads();
        if (w == 0 && lane < 16)
            out[bw * 16 + lane] =
                fcp[0][lane] + fcp[1][lane] + fcp[2][lane] + fcp[3][lane] + fc_b[0];
    }
}

extern "C" void kernel_launch(void* const* d_in, const int* in_sizes, int n_in,
                              void* d_out, int out_size, void* d_ws, size_t ws_size,
                              hipStream_t stream) {
    const float* x     = (const float*)d_in[0];
    const float* W_ih0 = (const float*)d_in[1];
    const float* W_hh0 = (const float*)d_in[2];
    const float* b_ih0 = (const float*)d_in[3];
    const float* b_hh0 = (const float*)d_in[4];
    const float* W_ih1 = (const float*)d_in[5];
    const float* W_hh1 = (const float*)d_in[6];
    const float* b_ih1 = (const float*)d_in[7];
    const float* b_hh1 = (const float*)d_in[8];
    const float* fc_W  = (const float*)d_in[9];
    const float* fc_b  = (const float*)d_in[10];

    rnn2_mfma_kernel<<<dim3(2048 / 16), dim3(256), 0, stream>>>(
        x, W_ih0, W_hh0, b_ih0, b_hh0, W_ih1, W_hh1, b_ih1, b_hh1,
        fc_W, fc_b, (float*)d_out);
}